// Round 6
// baseline (517.439 us; speedup 1.0000x reference)
//
#include <hip/hip_runtime.h>
#include <hip/hip_bf16.h>
#include <math.h>

#define B_ROWS 1024
#define V_COLS 50257
#define E_DIM  128
#define BM     128
#define BN     128
#define NNB    393                 // ceil(V_COLS / BN)
#define VPAD   (NNB * BN)          // 50304
#define N4     (V_COLS * E_DIM / 4)   // 1608224
#define N4P    (VPAD * E_DIM / 4)     // 1609728
#define NCHUNK 32                  // N-tile chunks per m-panel; grid = 8*32 = 256 blocks
#define CVT_BLOCKS ((N4P + 255) / 256)          // 6288
#define FI_BLOCKS  ((B_ROWS * V_COLS / 4 + 255) / 256)  // 50257 (exact: n4 = 50257*256)

typedef __attribute__((ext_vector_type(8))) short short8;
typedef __attribute__((ext_vector_type(4))) float floatx4;

static __device__ __forceinline__ unsigned short f2bf(float x) {
    union { float f; unsigned int u; } c; c.f = x;
    unsigned int u = c.u;
    unsigned int r = u + 0x7fffu + ((u >> 16) & 1u);
    return (unsigned short)(r >> 16);
}

// async global->LDS, 16B per lane; LDS dest = wave-uniform base + lane*16 (linear),
// swizzle applied on the per-lane GLOBAL address (m104/m173 pattern).
static __device__ __forceinline__ void gload16(const void* g, void* l) {
    __builtin_amdgcn_global_load_lds(
        (const __attribute__((address_space(1))) void*)g,
        (__attribute__((address_space(3))) void*)l,
        16, 0, 0);
}

// ---------------------------------------------------------------- fused prep:
// blocks [0, CVT_BLOCKS)              : NEG fp32 -> bf16 (padded)
// blocks [CVT_BLOCKS, +FI_BLOCKS)     : find one-hot index in xs
// Independent outputs -> no sync needed; streams run concurrently.
__global__ void prep_kernel(const float* __restrict__ xs, int* __restrict__ idx,
                            const float* __restrict__ NEG, ushort4* __restrict__ dst) {
    const int bid = blockIdx.x;
    if (bid < CVT_BLOCKS) {
        int i = bid * 256 + threadIdx.x;
        if (i >= N4P) return;
        ushort4 o;
        if (i < N4) {
            floatx4 v = __builtin_nontemporal_load((const floatx4*)NEG + i);
            o.x = f2bf(v.x); o.y = f2bf(v.y); o.z = f2bf(v.z); o.w = f2bf(v.w);
        } else {
            o.x = 0; o.y = 0; o.z = 0; o.w = 0;
        }
        dst[i] = o;
    } else {
        long i = (long)(bid - CVT_BLOCKS) * 256 + threadIdx.x;
        const long n4 = (long)B_ROWS * V_COLS / 4;
        if (i >= n4) return;
        floatx4 v = __builtin_nontemporal_load((const floatx4*)xs + i);
        float vals[4] = {v.x, v.y, v.z, v.w};
        #pragma unroll
        for (int c = 0; c < 4; ++c) {
            if (vals[c] != 0.0f) {
                long f = 4 * i + c;
                int b = (int)(f / V_COLS);
                idx[b] = (int)(f - (long)b * V_COLS);
            }
        }
    }
}

// ---------------------------------------------------------------- t[b] = EMBEDM[idx[b]] @ metric  (bf16 out)
__global__ void compute_t_kernel(const float* __restrict__ EMB, const float* __restrict__ metric,
                                 const int* __restrict__ idx, unsigned short* __restrict__ t) {
    __shared__ float erow[E_DIM];
    int b = blockIdx.x, tid = threadIdx.x;
    int id = idx[b];
    erow[tid] = EMB[(long)id * E_DIM + tid];
    __syncthreads();
    float acc = 0.f;
    #pragma unroll 16
    for (int k = 0; k < E_DIM; ++k) acc += erow[k] * metric[k * E_DIM + tid];
    t[b * E_DIM + tid] = f2bf(acc);
}

// ---------------------------------------------------------------- chunked multi-tile MFMA GEMM
// 256 blocks (1/CU), 512 thr = 8 waves (2 wm x 4 wn). Block owns m-panel (128 rows) x ~13 N-tiles.
// A-frags in registers; B double-buffered in LDS via global_load_lds (prefetch before compute).
// Pass LSE (WRITE_OUT=0): defer-max online sumexp in regs -> partials.
// Pass OUT (WRITE_OUT=1): nontemporal-writes score - lse directly.
template <bool WRITE_OUT>
__global__ __launch_bounds__(512, 2) void gemm_chunk_kernel(const unsigned short* __restrict__ t,
                                                            const unsigned short* __restrict__ neg,
                                                            float2* __restrict__ partials,
                                                            const float* __restrict__ lse,
                                                            float* __restrict__ out) {
    __shared__ __align__(16) uint4 bbuf[2][2048];   // 2 x 32KB B tiles

    const int lin  = blockIdx.x;
    // XCD-chunk mapping: the 8 m-blocks sharing chunk c land on the same XCD (lin%8 == c%8)
    const int m    = (lin >> 3) & 7;
    const int c    = (lin & 7) | ((lin >> 6) << 3);
    const int t0   = (c * NNB) / NCHUNK;
    const int t1   = ((c + 1) * NNB) / NCHUNK;

    const int tid  = threadIdx.x;
    const int lane = tid & 63, wave = tid >> 6;
    const int l16  = lane & 15, q = lane >> 4;
    const int wm   = wave >> 2, wn = wave & 3;       // 2x4 wave grid; wave = 64 rows x 32 cols
    const int mbase = m * BM;

    // ---- A fragments in registers: af[mf][ks], row = mbase+wm*64+mf*16+l16, k = ks*32+q*8
    short8 af[4][4];
    #pragma unroll
    for (int mf = 0; mf < 4; ++mf)
        #pragma unroll
        for (int ks = 0; ks < 4; ++ks)
            af[mf][ks] = *(const short8*)&t[(size_t)(mbase + wm * 64 + mf * 16 + l16) * E_DIM + ks * 32 + q * 8];

    // per-row state
    float lsev[4][4];
    float mrun[4][4], srun[4][4];
    if (WRITE_OUT) {
        #pragma unroll
        for (int mf = 0; mf < 4; ++mf)
            #pragma unroll
            for (int r = 0; r < 4; ++r)
                lsev[mf][r] = lse[mbase + wm * 64 + mf * 16 + q * 4 + r];
    } else {
        #pragma unroll
        for (int mf = 0; mf < 4; ++mf)
            #pragma unroll
            for (int r = 0; r < 4; ++r) { mrun[mf][r] = -INFINITY; srun[mf][r] = 0.f; }
    }

    // ---- staging helper: tile -> bbuf[buf] (2048 chunks of 16B, src-swizzled, LDS linear)
    const int p0 = wave * 256 + lane;
    auto STAGE = [&](int buf, int tile) {
        const uint4* srcB = (const uint4*)(neg + (size_t)tile * BN * E_DIM);
        #pragma unroll
        for (int i = 0; i < 4; ++i) {
            int p = p0 + i * 64;
            int r = p >> 4, cc = p & 15;
            int s = (r << 4) + (cc ^ (r & 15));
            gload16(srcB + s, &bbuf[buf][wave * 256 + i * 64]);
        }
    };

    STAGE(0, t0);
    __syncthreads();

    for (int tt = t0; tt < t1; ++tt) {
        const int cur = (tt - t0) & 1;
        if (tt + 1 < t1) STAGE(cur ^ 1, tt + 1);   // prefetch next while computing cur

        floatx4 acc[4][2];
        #pragma unroll
        for (int i = 0; i < 4; ++i)
            #pragma unroll
            for (int j = 0; j < 2; ++j) acc[i][j] = (floatx4){0, 0, 0, 0};

        #pragma unroll
        for (int ks = 0; ks < 4; ++ks) {
            short8 bfr[2];
            #pragma unroll
            for (int nf = 0; nf < 2; ++nf) {
                int row = wn * 32 + nf * 16 + l16;
                bfr[nf] = *(const short8*)&bbuf[cur][(row << 4) + ((ks * 4 + q) ^ (row & 15))];
            }
            #pragma unroll
            for (int mf = 0; mf < 4; ++mf)
                #pragma unroll
                for (int nf = 0; nf < 2; ++nf)
                    acc[mf][nf] = __builtin_amdgcn_mfma_f32_16x16x32_bf16(af[mf][ks], bfr[nf], acc[mf][nf], 0, 0, 0);
        }

        // acc[mf][nf][r]: row = mbase+wm*64+mf*16+q*4+r, col = tt*128 + wn*32 + nf*16 + l16
        const bool tail = ((tt + 1) * BN > V_COLS);   // only the very last tile (392)
        const int  col0 = tt * BN + wn * 32 + l16;

        if (!WRITE_OUT) {
            if (!tail) {
                // fast path: defer-max online sumexp (exact: a - m <= 8 at insert time)
                #pragma unroll
                for (int mf = 0; mf < 4; ++mf)
                    #pragma unroll
                    for (int r = 0; r < 4; ++r) {
                        float a0 = acc[mf][0][r], a1 = acc[mf][1][r];
                        float pm = fmaxf(a0, a1);
                        float m0 = mrun[mf][r];
                        if (pm > m0 + 8.f) { srun[mf][r] *= __expf(m0 - pm); mrun[mf][r] = pm; m0 = pm; }
                        srun[mf][r] += __expf(a0 - m0) + __expf(a1 - m0);
                    }
            } else {
                const bool v0 = col0 < V_COLS;
                const bool v1 = (col0 + 16) < V_COLS;
                #pragma unroll
                for (int mf = 0; mf < 4; ++mf)
                    #pragma unroll
                    for (int r = 0; r < 4; ++r) {
                        float a0 = v0 ? acc[mf][0][r] : -INFINITY;
                        float a1 = v1 ? acc[mf][1][r] : -INFINITY;
                        float pm = fmaxf(a0, a1);
                        float m0 = mrun[mf][r];
                        if (pm > m0 + 8.f) { srun[mf][r] *= __expf(m0 - pm); mrun[mf][r] = pm; m0 = pm; }
                        if (v0) srun[mf][r] += __expf(a0 - m0);
                        if (v1) srun[mf][r] += __expf(a1 - m0);
                    }
            }
        } else {
            if (!tail) {
                #pragma unroll
                for (int mf = 0; mf < 4; ++mf) {
                    const size_t rowb = (size_t)(mbase + wm * 64 + mf * 16 + q * 4) * V_COLS;
                    #pragma unroll
                    for (int r = 0; r < 4; ++r) {
                        __builtin_nontemporal_store(acc[mf][0][r] - lsev[mf][r],
                                                    &out[rowb + (size_t)r * V_COLS + col0]);
                        __builtin_nontemporal_store(acc[mf][1][r] - lsev[mf][r],
                                                    &out[rowb + (size_t)r * V_COLS + col0 + 16]);
                    }
                }
            } else {
                const bool v0 = col0 < V_COLS;
                const bool v1 = (col0 + 16) < V_COLS;
                #pragma unroll
                for (int mf = 0; mf < 4; ++mf) {
                    const size_t rowb = (size_t)(mbase + wm * 64 + mf * 16 + q * 4) * V_COLS;
                    #pragma unroll
                    for (int r = 0; r < 4; ++r) {
                        if (v0) __builtin_nontemporal_store(acc[mf][0][r] - lsev[mf][r],
                                                            &out[rowb + (size_t)r * V_COLS + col0]);
                        if (v1) __builtin_nontemporal_store(acc[mf][1][r] - lsev[mf][r],
                                                            &out[rowb + (size_t)r * V_COLS + col0 + 16]);
                    }
                }
            }
        }
        __syncthreads();   // everyone done with bbuf[cur]; prefetch into cur^1 drained
    }

    if (!WRITE_OUT) {
        // cross-lane merge over the 16 l16 lanes (same row, different cols)
        #pragma unroll
        for (int mf = 0; mf < 4; ++mf)
            #pragma unroll
            for (int r = 0; r < 4; ++r) {
                float mm = mrun[mf][r], ss = srun[mf][r];
                #pragma unroll
                for (int d = 1; d < 16; d <<= 1) {
                    float mo = __shfl_xor(mm, d, 16);
                    float so = __shfl_xor(ss, d, 16);
                    float nm = fmaxf(mm, mo);
                    ss = ss * __expf(mm - nm) + so * __expf(mo - nm);
                    mm = nm;
                }
                if (l16 == 0) {
                    int row_local = wm * 64 + mf * 16 + q * 4 + r;
                    partials[(((size_t)mbase + row_local) * NCHUNK + c) * 4 + wn] = make_float2(mm, ss);
                }
            }
    }
}

// ---------------------------------------------------------------- merge 128 partials/row -> lse[b]
__global__ __launch_bounds__(128) void merge_lse_kernel(const float2* __restrict__ partials,
                                                        float* __restrict__ lse) {
    int b = blockIdx.x, tid = threadIdx.x;
    float2 p = partials[(size_t)b * 128 + tid];
    float mm = p.x, ss = p.y;
    #pragma unroll
    for (int d = 1; d < 64; d <<= 1) {
        float mo = __shfl_xor(mm, d, 64);
        float so = __shfl_xor(ss, d, 64);
        float nm = fmaxf(mm, mo);
        ss = ss * __expf(mm - nm) + so * __expf(mo - nm);
        mm = nm;
    }
    __shared__ float m2[2], s2[2];
    if ((tid & 63) == 0) { m2[tid >> 6] = mm; s2[tid >> 6] = ss; }
    __syncthreads();
    if (tid == 0) {
        float nm = fmaxf(m2[0], m2[1]);
        float s  = s2[0] * __expf(m2[0] - nm) + s2[1] * __expf(m2[1] - nm);
        lse[b] = nm + __logf(s);
    }
}

// ---------------------------------------------------------------- launch
extern "C" void kernel_launch(void* const* d_in, const int* in_sizes, int n_in,
                              void* d_out, int out_size, void* d_ws, size_t ws_size,
                              hipStream_t stream) {
    const float* xs     = (const float*)d_in[0];
    const float* metric = (const float*)d_in[1];
    const float* EMB    = (const float*)d_in[2];
    const float* NEG    = (const float*)d_in[3];
    float* out = (float*)d_out;

    char* ws = (char*)d_ws;
    // layout: idx[1024] | t bf16[1024*128] | neg bf16[VPAD*128] | partials float2[1024*128] | lse[1024]
    int*            idx      = (int*)ws;                               // 4096 B
    unsigned short* t        = (unsigned short*)(ws + 4096);           // 262144 -> 266240
    unsigned short* neg16    = (unsigned short*)(ws + 266240);         // 12877824 -> 13144064
    float2*         partials = (float2*)(ws + 13144064);               // 1024*128*8 = 1048576 -> 14192640
    float*          lse      = (float*)(ws + 14192640);                // 4096 B

    prep_kernel<<<CVT_BLOCKS + FI_BLOCKS, 256, 0, stream>>>(xs, idx, NEG, (ushort4*)neg16);
    compute_t_kernel<<<B_ROWS, E_DIM, 0, stream>>>(EMB, metric, idx, t);
    gemm_chunk_kernel<false><<<8 * NCHUNK, 512, 0, stream>>>(t, neg16, partials, nullptr, nullptr);
    merge_lse_kernel<<<B_ROWS, 128, 0, stream>>>(partials, lse);
    gemm_chunk_kernel<true><<<8 * NCHUNK, 512, 0, stream>>>(t, neg16, partials, lse, out);
}

// Round 7
// 445.197 us; speedup vs baseline: 1.1623x; 1.1623x over previous
//
#include <hip/hip_runtime.h>
#include <hip/hip_bf16.h>
#include <math.h>

#define B_ROWS 1024
#define V_COLS 50257
#define E_DIM  128
#define BM     128
#define BN     128
#define NNB    393                 // ceil(V_COLS / BN)
#define VPAD   (NNB * BN)          // 50304
#define N4     (V_COLS * E_DIM / 4)   // 1608224
#define N4P    (VPAD * E_DIM / 4)     // 1609728
#define NCHUNK 64                  // N-tile chunks per m-panel; grid = 8*64 = 512 blocks (2/CU)

typedef __attribute__((ext_vector_type(8))) short short8;
typedef __attribute__((ext_vector_type(4))) float floatx4;

static __device__ __forceinline__ unsigned short f2bf(float x) {
    union { float f; unsigned int u; } c; c.f = x;
    unsigned int u = c.u;
    unsigned int r = u + 0x7fffu + ((u >> 16) & 1u);
    return (unsigned short)(r >> 16);
}

// async global->LDS, 16B per lane; LDS dest = wave-uniform base + lane*16 (linear),
// swizzle applied on the per-lane GLOBAL address (m104/m173 pattern).
static __device__ __forceinline__ void gload16(const void* g, void* l) {
    __builtin_amdgcn_global_load_lds(
        (const __attribute__((address_space(1))) void*)g,
        (__attribute__((address_space(3))) void*)l,
        16, 0, 0);
}

// ---------------------------------------------------------------- find one-hot index
__global__ void find_idx_kernel(const float* __restrict__ xs, int* __restrict__ idx) {
    long i = (long)blockIdx.x * blockDim.x + threadIdx.x;
    const long n4 = (long)B_ROWS * V_COLS / 4;
    if (i >= n4) return;
    floatx4 v = __builtin_nontemporal_load((const floatx4*)xs + i);
    float vals[4] = {v.x, v.y, v.z, v.w};
    #pragma unroll
    for (int c = 0; c < 4; ++c) {
        if (vals[c] != 0.0f) {
            long f = 4 * i + c;
            int b = (int)(f / V_COLS);
            idx[b] = (int)(f - (long)b * V_COLS);
        }
    }
}

// ---------------------------------------------------------------- NEG fp32 -> bf16 (padded to VPAD rows, zeros)
__global__ void cvt_bf16_kernel(const float* __restrict__ src, ushort4* __restrict__ dst) {
    int i = blockIdx.x * blockDim.x + threadIdx.x;
    if (i >= N4P) return;
    ushort4 o;
    if (i < N4) {
        floatx4 v = __builtin_nontemporal_load((const floatx4*)src + i);
        o.x = f2bf(v.x); o.y = f2bf(v.y); o.z = f2bf(v.z); o.w = f2bf(v.w);
    } else {
        o.x = 0; o.y = 0; o.z = 0; o.w = 0;
    }
    dst[i] = o;
}

// ---------------------------------------------------------------- t[b] = EMBEDM[idx[b]] @ metric  (bf16 out)
__global__ void compute_t_kernel(const float* __restrict__ EMB, const float* __restrict__ metric,
                                 const int* __restrict__ idx, unsigned short* __restrict__ t) {
    __shared__ float erow[E_DIM];
    int b = blockIdx.x, tid = threadIdx.x;
    int id = idx[b];
    erow[tid] = EMB[(long)id * E_DIM + tid];
    __syncthreads();
    float acc = 0.f;
    #pragma unroll 16
    for (int k = 0; k < E_DIM; ++k) acc += erow[k] * metric[k * E_DIM + tid];
    t[b * E_DIM + tid] = f2bf(acc);
}

// ---------------------------------------------------------------- chunked multi-tile MFMA GEMM
// 512 blocks (2/CU), 512 thr = 8 waves (2 wm x 4 wn). Block owns m-panel (128 rows) x ~6 N-tiles.
// A-frags in registers (from L2-hot t); B double-buffered in LDS via global_load_lds.
// 2 blocks/CU so one block's barrier/vmcnt drain overlaps the other's compute.
// Pass LSE (WRITE_OUT=0): online (max,sumexp) in regs across tiles -> partials.
// Pass OUT (WRITE_OUT=1): writes score - lse directly.
template <bool WRITE_OUT>
__global__ __launch_bounds__(512, 2) void gemm_chunk_kernel(const unsigned short* __restrict__ t,
                                                            const unsigned short* __restrict__ neg,
                                                            float2* __restrict__ partials,
                                                            const float* __restrict__ lse,
                                                            float* __restrict__ out) {
    __shared__ __align__(16) uint4 bbuf[2][2048];   // 2 x 32KB B tiles

    const int lin  = blockIdx.x;
    // XCD-chunk mapping: the 8 m-blocks sharing chunk c satisfy lin%8 == c%8 -> same XCD
    const int m    = (lin >> 3) & 7;
    const int c    = (lin & 7) | ((lin >> 6) << 3);
    const int t0   = (c * NNB) / NCHUNK;
    const int t1   = ((c + 1) * NNB) / NCHUNK;

    const int tid  = threadIdx.x;
    const int lane = tid & 63, wave = tid >> 6;
    const int l16  = lane & 15, q = lane >> 4;
    const int wm   = wave >> 2, wn = wave & 3;       // 2x4 wave grid; wave = 64 rows x 32 cols
    const int mbase = m * BM;

    // ---- A fragments in registers: af[mf][ks], row = mbase+wm*64+mf*16+l16, k = ks*32+q*8
    short8 af[4][4];
    #pragma unroll
    for (int mf = 0; mf < 4; ++mf)
        #pragma unroll
        for (int ks = 0; ks < 4; ++ks)
            af[mf][ks] = *(const short8*)&t[(size_t)(mbase + wm * 64 + mf * 16 + l16) * E_DIM + ks * 32 + q * 8];

    // per-row state
    float lsev[4][4];      // WRITE_OUT: lse per (mf,r)
    float mrun[4][4], srun[4][4];
    if (WRITE_OUT) {
        #pragma unroll
        for (int mf = 0; mf < 4; ++mf)
            #pragma unroll
            for (int r = 0; r < 4; ++r)
                lsev[mf][r] = lse[mbase + wm * 64 + mf * 16 + q * 4 + r];
    } else {
        #pragma unroll
        for (int mf = 0; mf < 4; ++mf)
            #pragma unroll
            for (int r = 0; r < 4; ++r) { mrun[mf][r] = -INFINITY; srun[mf][r] = 0.f; }
    }

    // ---- staging helper: tile -> bbuf[buf] (2048 chunks of 16B, src-swizzled, LDS linear)
    const int p0 = wave * 256 + lane;
    auto STAGE = [&](int buf, int tile) {
        const uint4* srcB = (const uint4*)(neg + (size_t)tile * BN * E_DIM);
        #pragma unroll
        for (int i = 0; i < 4; ++i) {
            int p = p0 + i * 64;
            int r = p >> 4, cc = p & 15;
            int s = (r << 4) + (cc ^ (r & 15));
            gload16(srcB + s, &bbuf[buf][wave * 256 + i * 64]);
        }
    };

    STAGE(0, t0);
    __syncthreads();

    for (int tt = t0; tt < t1; ++tt) {
        const int cur = (tt - t0) & 1;
        if (tt + 1 < t1) STAGE(cur ^ 1, tt + 1);   // prefetch next while computing cur

        floatx4 acc[4][2];
        #pragma unroll
        for (int i = 0; i < 4; ++i)
            #pragma unroll
            for (int j = 0; j < 2; ++j) acc[i][j] = (floatx4){0, 0, 0, 0};

        #pragma unroll
        for (int ks = 0; ks < 4; ++ks) {
            short8 bfr[2];
            #pragma unroll
            for (int nf = 0; nf < 2; ++nf) {
                int row = wn * 32 + nf * 16 + l16;
                bfr[nf] = *(const short8*)&bbuf[cur][(row << 4) + ((ks * 4 + q) ^ (row & 15))];
            }
            #pragma unroll
            for (int mf = 0; mf < 4; ++mf)
                #pragma unroll
                for (int nf = 0; nf < 2; ++nf)
                    acc[mf][nf] = __builtin_amdgcn_mfma_f32_16x16x32_bf16(af[mf][ks], bfr[nf], acc[mf][nf], 0, 0, 0);
        }

        // acc[mf][nf][r]: row = mbase+wm*64+mf*16+q*4+r, col = tt*128 + wn*32 + nf*16 + l16
        const int col0 = tt * BN + wn * 32 + l16;
        const bool v0 = col0 < V_COLS;
        const bool v1 = (col0 + 16) < V_COLS;

        if (!WRITE_OUT) {
            #pragma unroll
            for (int mf = 0; mf < 4; ++mf)
                #pragma unroll
                for (int r = 0; r < 4; ++r) {
                    float a0 = v0 ? acc[mf][0][r] : -INFINITY;
                    float a1 = v1 ? acc[mf][1][r] : -INFINITY;
                    float nm = fmaxf(mrun[mf][r], fmaxf(a0, a1));
                    float s  = srun[mf][r] * __expf(mrun[mf][r] - nm);
                    if (v0) s += __expf(a0 - nm);
                    if (v1) s += __expf(a1 - nm);
                    mrun[mf][r] = nm; srun[mf][r] = s;
                }
        } else {
            #pragma unroll
            for (int mf = 0; mf < 4; ++mf) {
                const size_t rowb = (size_t)(mbase + wm * 64 + mf * 16 + q * 4) * V_COLS;
                #pragma unroll
                for (int r = 0; r < 4; ++r) {
                    if (v0) out[rowb + (size_t)r * V_COLS + col0]      = acc[mf][0][r] - lsev[mf][r];
                    if (v1) out[rowb + (size_t)r * V_COLS + col0 + 16] = acc[mf][1][r] - lsev[mf][r];
                }
            }
        }
        __syncthreads();   // everyone done with bbuf[cur]; prefetch into cur^1 drained
    }

    if (!WRITE_OUT) {
        // cross-lane merge over the 16 l16 lanes (same row, different cols)
        #pragma unroll
        for (int mf = 0; mf < 4; ++mf)
            #pragma unroll
            for (int r = 0; r < 4; ++r) {
                float mm = mrun[mf][r], ss = srun[mf][r];
                #pragma unroll
                for (int d = 1; d < 16; d <<= 1) {
                    float mo = __shfl_xor(mm, d, 16);
                    float so = __shfl_xor(ss, d, 16);
                    float nm = fmaxf(mm, mo);
                    ss = ss * __expf(mm - nm) + so * __expf(mo - nm);
                    mm = nm;
                }
                if (l16 == 0) {
                    int row_local = wm * 64 + mf * 16 + q * 4 + r;
                    partials[(((size_t)mbase + row_local) * NCHUNK + c) * 4 + wn] = make_float2(mm, ss);
                }
            }
    }
}

// ---------------------------------------------------------------- merge 256 partials/row -> lse[b]
__global__ __launch_bounds__(256) void merge_lse_kernel(const float2* __restrict__ partials,
                                                        float* __restrict__ lse) {
    int b = blockIdx.x, tid = threadIdx.x;
    float2 p = partials[(size_t)b * (NCHUNK * 4) + tid];
    float mm = p.x, ss = p.y;
    // reduce within each wave (64), then across the 4 waves via LDS
    #pragma unroll
    for (int d = 1; d < 64; d <<= 1) {
        float mo = __shfl_xor(mm, d, 64);
        float so = __shfl_xor(ss, d, 64);
        float nm = fmaxf(mm, mo);
        ss = ss * __expf(mm - nm) + so * __expf(mo - nm);
        mm = nm;
    }
    __shared__ float m4[4], s4[4];
    if ((tid & 63) == 0) { m4[tid >> 6] = mm; s4[tid >> 6] = ss; }
    __syncthreads();
    if (tid == 0) {
        float rm = fmaxf(fmaxf(m4[0], m4[1]), fmaxf(m4[2], m4[3]));
        float rs = s4[0] * __expf(m4[0] - rm) + s4[1] * __expf(m4[1] - rm)
                 + s4[2] * __expf(m4[2] - rm) + s4[3] * __expf(m4[3] - rm);
        lse[b] = rm + __logf(rs);
    }
}

// ---------------------------------------------------------------- launch
extern "C" void kernel_launch(void* const* d_in, const int* in_sizes, int n_in,
                              void* d_out, int out_size, void* d_ws, size_t ws_size,
                              hipStream_t stream) {
    const float* xs     = (const float*)d_in[0];
    const float* metric = (const float*)d_in[1];
    const float* EMB    = (const float*)d_in[2];
    const float* NEG    = (const float*)d_in[3];
    float* out = (float*)d_out;

    char* ws = (char*)d_ws;
    // layout: idx[1024] | t bf16[1024*128] | neg bf16[VPAD*128] | partials float2[1024*256] | lse[1024]
    int*            idx      = (int*)ws;                               // 4096 B
    unsigned short* t        = (unsigned short*)(ws + 4096);           // 262144 -> 266240
    unsigned short* neg16    = (unsigned short*)(ws + 266240);         // 12877824 -> 13144064
    float2*         partials = (float2*)(ws + 13144064);               // 1024*256*8 = 2097152 -> 15241216
    float*          lse      = (float*)(ws + 15241216);                // 4096 B

    {
        long n4 = (long)B_ROWS * V_COLS / 4;
        int blocks = (int)((n4 + 255) / 256);
        find_idx_kernel<<<blocks, 256, 0, stream>>>(xs, idx);
    }
    cvt_bf16_kernel<<<(N4P + 255) / 256, 256, 0, stream>>>(NEG, (ushort4*)neg16);
    compute_t_kernel<<<B_ROWS, E_DIM, 0, stream>>>(EMB, metric, idx, t);
    gemm_chunk_kernel<false><<<8 * NCHUNK, 512, 0, stream>>>(t, neg16, partials, nullptr, nullptr);
    merge_lse_kernel<<<B_ROWS, 256, 0, stream>>>(partials, lse);
    gemm_chunk_kernel<true><<<8 * NCHUNK, 512, 0, stream>>>(t, neg16, partials, lse, out);
}